// Round 5
// baseline (1772.468 us; speedup 1.0000x reference)
//
#include <hip/hip_runtime.h>
#include <hip/hip_bf16.h>

// ---------------------------------------------------------------------------
// GCN graph classifier: 2x GCNConv(relu) -> mean pool -> MLP -> sigmoid
// Round 5 structure:
//   out[d] = dinv[d]*(h'[d] + sum_{s in N(d)} h'[s]),  h' = dinv*(A@W)
//   -> no per-edge norm; 4B edge records binned by 128-node dst tile with
//   per-(tile, xcd) cursors (write-combine friendly); aggregation = one
//   block per tile with fp32 LDS accumulator + LDS atomics; degrees from
//   the bin (no global histogram). bf16 h', fp32 accum, MFMA GEMMs.
// ---------------------------------------------------------------------------

#define TILE 128  // dst nodes per tile; LDS acc = 128*128*4B = 64KB

using short8 = __attribute__((ext_vector_type(8))) short;   // 8 bf16 (4 VGPR)
using f32x4  = __attribute__((ext_vector_type(4))) float;   // MFMA accum

__device__ inline unsigned short f2bf(float f) {  // RNE fp32 -> bf16
    unsigned u = __float_as_uint(f);
    u = (u + 0x7fff + ((u >> 16) & 1)) >> 16;
    return (unsigned short)u;
}
__device__ inline float bf2f(unsigned short b) {
    return __uint_as_float((unsigned)b << 16);
}

// ---- zero: per-(tile,xcd) counters + pooled accumulator --------------------
__global__ __launch_bounds__(256) void k_zero(int* __restrict__ cnt,
                                              float* __restrict__ pooled,
                                              int m) {
    int i = blockIdx.x * 256 + threadIdx.x;
    if (i < m) cnt[i] = 0;
    if (blockIdx.x == 0 && threadIdx.x < 128) pooled[threadIdx.x] = 0.0f;
}

// ---- binA: count edges per (dst tile, xcd-proxy) ---------------------------
__global__ __launch_bounds__(256) void k_binA(const int* __restrict__ dst,
                                              int* __restrict__ cnt, int e) {
    int i = blockIdx.x * 256 + threadIdx.x;
    if (i < e) {
        int t = dst[i] >> 7;
        atomicAdd(&cnt[t * 8 + (blockIdx.x & 7)], 1);
    }
}

// ---- scan of M counters (single block, serial chunks with carry) -----------
__global__ __launch_bounds__(256) void k_scanM(const int* __restrict__ cnt,
                                               int* __restrict__ start,
                                               int* __restrict__ cursor, int m,
                                               int etot) {
    __shared__ int sh[256];
    __shared__ int carry;
    const int tid = threadIdx.x;
    if (tid == 0) carry = 0;
    __syncthreads();
    const int nchunk = (m + 255) / 256;
    for (int c = 0; c < nchunk; ++c) {
        int i = c * 256 + tid;
        int v = (i < m) ? cnt[i] : 0;
        sh[tid] = v;
        __syncthreads();
        for (int o = 1; o < 256; o <<= 1) {
            int t = (tid >= o) ? sh[tid - o] : 0;
            __syncthreads();
            sh[tid] += t;
            __syncthreads();
        }
        int excl = sh[tid] - v + carry;
        if (i < m) {
            start[i] = excl;
            cursor[i] = excl;
        }
        __syncthreads();
        if (tid == 255) carry += sh[255];
        __syncthreads();
    }
    if (tid == 0) start[m] = etot;
}

// ---- binB: append 4B record (src<<7 | dst&127) via per-(tile,xcd) cursor ---
__global__ __launch_bounds__(256) void k_binB(const int* __restrict__ ei,
                                              int* __restrict__ cursor,
                                              unsigned* __restrict__ bin,
                                              int e) {
    int i = blockIdx.x * 256 + threadIdx.x;
    if (i < e) {
        int s = ei[i];
        int d = ei[e + i];
        int t = d >> 7;
        int pos = atomicAdd(&cursor[t * 8 + (blockIdx.x & 7)], 1);
        bin[pos] = ((unsigned)s << 7) | (unsigned)(d & 127);
    }
}

// ---- per-tile degree count (LDS histogram) -> dinv -------------------------
__global__ __launch_bounds__(256) void k_degdinv(const unsigned* __restrict__ bin,
                                                 const int* __restrict__ start,
                                                 float* __restrict__ dinv,
                                                 int n) {
    __shared__ int deg[TILE];
    const int t = blockIdx.x, tid = threadIdx.x;
    if (tid < TILE) deg[tid] = 0;
    __syncthreads();
    const int b = start[t * 8], e = start[t * 8 + 8];
    for (int j = b + tid; j < e; j += 256) atomicAdd(&deg[bin[j] & 127], 1);
    __syncthreads();
    const int node = t * TILE + tid;
    if (tid < TILE && node < n)
        dinv[node] = rsqrtf((float)deg[tid] + 1.0f);
}

// ---- prep: convert both 128x128 weights to pre-fragged bf16 MFMA layout ----
// wf[((ct*4+ks)*64+l)*8+j] = W[ks*32 + (l>>4)*8 + j][ct*16 + (l&15)]
__global__ __launch_bounds__(256) void k_prepw(const float* __restrict__ w1,
                                               const float* __restrict__ w2,
                                               unsigned short* __restrict__ wf1,
                                               unsigned short* __restrict__ wf2) {
    int t = blockIdx.x * 256 + threadIdx.x;  // 0..32767
    int i = t & 16383;
    int j = i & 7;
    int l = (i >> 3) & 63;
    int ks = (i >> 9) & 3;
    int ct = (i >> 11) & 7;
    int k = ks * 32 + (l >> 4) * 8 + j;
    int c = ct * 16 + (l & 15);
    if (t < 16384)
        wf1[i] = f2bf(w1[k * 128 + c]);
    else
        wf2[i] = f2bf(w2[k * 128 + c]);
}

// ---- MFMA bf16 GEMM + dinv-scale epilogue: C = dinv[r]*(A@W), bf16 out -----
// 4 waves/block, 16 rows/wave. 16x16x32 frags; D: col=lane&15, row=(lane>>4)*4+i
template <bool AFP32>
__global__ __launch_bounds__(256) void k_gemm_mfma(
    const void* __restrict__ Ain, const unsigned short* __restrict__ Wf,
    const float* __restrict__ dinv, unsigned short* __restrict__ Cout,
    int nrows) {
    const int tid = threadIdx.x;
    const int wave = tid >> 6, l = tid & 63;
    const int r0w = blockIdx.x * 64 + wave * 16;
    const int mrow = l & 15, koff = (l >> 4) * 8;
    int r = r0w + mrow;
    int rload = (r < nrows) ? r : 0;

    short8 afr[4];
    if (AFP32) {
        const float* A = (const float*)Ain;
#pragma unroll
        for (int ks = 0; ks < 4; ++ks) {
            const float4 lo = *(const float4*)&A[(size_t)rload * 128 + ks * 32 + koff];
            const float4 hi = *(const float4*)&A[(size_t)rload * 128 + ks * 32 + koff + 4];
            short8 t;
            t[0] = (short)f2bf(lo.x); t[1] = (short)f2bf(lo.y);
            t[2] = (short)f2bf(lo.z); t[3] = (short)f2bf(lo.w);
            t[4] = (short)f2bf(hi.x); t[5] = (short)f2bf(hi.y);
            t[6] = (short)f2bf(hi.z); t[7] = (short)f2bf(hi.w);
            afr[ks] = t;
        }
    } else {
        const unsigned short* A = (const unsigned short*)Ain;
#pragma unroll
        for (int ks = 0; ks < 4; ++ks)
            afr[ks] = *(const short8*)&A[(size_t)rload * 128 + ks * 32 + koff];
    }

    f32x4 acc[8];
#pragma unroll
    for (int ct = 0; ct < 8; ++ct) acc[ct] = (f32x4){0.f, 0.f, 0.f, 0.f};

#pragma unroll
    for (int ct = 0; ct < 8; ++ct) {
#pragma unroll
        for (int ks = 0; ks < 4; ++ks) {
            const short8 b = *(const short8*)&Wf[((ct * 4 + ks) * 64 + l) * 8];
            acc[ct] = __builtin_amdgcn_mfma_f32_16x16x32_bf16(afr[ks], b,
                                                              acc[ct], 0, 0, 0);
        }
    }

    const int rs0 = r0w + (l >> 4) * 4;
    const int cc = l & 15;
    float dv[4];
#pragma unroll
    for (int i = 0; i < 4; ++i)
        dv[i] = (rs0 + i < nrows) ? dinv[rs0 + i] : 0.f;
#pragma unroll
    for (int ct = 0; ct < 8; ++ct) {
#pragma unroll
        for (int i = 0; i < 4; ++i) {
            const int rr = rs0 + i;
            if (rr < nrows)
                Cout[(size_t)rr * 128 + ct * 16 + cc] = f2bf(acc[ct][i] * dv[i]);
        }
    }
}

// ---- tiled aggregation: block per 128-node dst tile, fp32 LDS accum --------
// out[d] = relu(dinv[d]*(acc[d] + h'[d]) + bias)
__global__ __launch_bounds__(256) void k_aggT(
    const unsigned* __restrict__ hp,  // h' rows as uint[n][64] (2 bf16/uint)
    const float* __restrict__ dinv, const unsigned* __restrict__ bin,
    const int* __restrict__ start, const float* __restrict__ bias,
    unsigned* __restrict__ outp, int n) {
    __shared__ float acc[TILE * 128];
    const int tid = threadIdx.x, wave = tid >> 6, lane = tid & 63;
    const int t = blockIdx.x;

    for (int i = tid; i < TILE * 128 / 4; i += 256)
        *(float4*)&acc[i * 4] = make_float4(0.f, 0.f, 0.f, 0.f);
    __syncthreads();

    const int b0 = start[t * 8], e0 = start[t * 8 + 8];
    for (int base = b0 + wave * 64; base < e0; base += 256) {
        const int cnt64 = min(64, e0 - base);
        int myrec = (base + lane < e0) ? (int)bin[base + lane] : -1;
        if (cnt64 == 64) {
            for (int i = 0; i < 64; i += 8) {
                int r[8];
                unsigned v[8];
#pragma unroll
                for (int k = 0; k < 8; ++k) r[k] = __shfl(myrec, i + k);
#pragma unroll
                for (int k = 0; k < 8; ++k)
                    v[k] = hp[(size_t)((unsigned)r[k] >> 7) * 64 + lane];
#pragma unroll
                for (int k = 0; k < 8; ++k) {
                    const unsigned u = v[k];
                    const int nl = r[k] & 127;
                    atomicAdd(&acc[nl * 128 + 2 * lane],
                              bf2f((unsigned short)(u & 0xffff)));
                    atomicAdd(&acc[nl * 128 + 2 * lane + 1],
                              bf2f((unsigned short)(u >> 16)));
                }
            }
        } else {
            for (int i = 0; i < cnt64; ++i) {
                const int r = __shfl(myrec, i);
                const unsigned u = hp[(size_t)((unsigned)r >> 7) * 64 + lane];
                const int nl = r & 127;
                atomicAdd(&acc[nl * 128 + 2 * lane],
                          bf2f((unsigned short)(u & 0xffff)));
                atomicAdd(&acc[nl * 128 + 2 * lane + 1],
                          bf2f((unsigned short)(u >> 16)));
            }
        }
    }
    __syncthreads();

    const float2 bp = *(const float2*)&bias[2 * lane];
    for (int i = wave; i < TILE; i += 4) {
        const int node = t * TILE + i;
        if (node >= n) break;
        const float dv = dinv[node];
        const unsigned su = hp[(size_t)node * 64 + lane];
        const float2 a = *(const float2*)&acc[i * 128 + 2 * lane];
        const float ox =
            fmaxf((a.x + bf2f((unsigned short)(su & 0xffff))) * dv + bp.x, 0.f);
        const float oy =
            fmaxf((a.y + bf2f((unsigned short)(su >> 16))) * dv + bp.y, 0.f);
        outp[(size_t)node * 64 + lane] =
            ((unsigned)f2bf(oy) << 16) | f2bf(ox);
    }
}

// ---- mean pool over bf16 [n,128]: block partials + atomic combine ----------
__global__ __launch_bounds__(256) void k_pool_bf16(
    const unsigned short* __restrict__ a, float* __restrict__ pooled,
    int npairs) {  // npairs = n*64 (uint = 2 cols)
    __shared__ float px[256], py[256];
    const int tid = threadIdx.x;
    float sx = 0.f, sy = 0.f;
    for (size_t idx = (size_t)blockIdx.x * 256 + tid; idx < (size_t)npairs;
         idx += (size_t)gridDim.x * 256) {
        const unsigned v = *(const unsigned*)&a[idx * 2];
        sx += bf2f((unsigned short)(v & 0xffff));
        sy += bf2f((unsigned short)(v >> 16));
    }
    px[tid] = sx;
    py[tid] = sy;
    __syncthreads();
    if (tid < 64) {
        const int c = tid;
        float ax = px[c] + px[c + 64] + px[c + 128] + px[c + 192];
        float ay = py[c] + py[c + 64] + py[c + 128] + py[c + 192];
        atomicAdd(&pooled[2 * c], ax);
        atomicAdd(&pooled[2 * c + 1], ay);
    }
}

// ---- MLP head: single block, 128 threads -----------------------------------
__global__ __launch_bounds__(128) void k_mlp(
    const float* __restrict__ pooled, const float* __restrict__ w11,
    const float* __restrict__ b11, const float* __restrict__ w12,
    const float* __restrict__ b12, const float* __restrict__ w21,
    const float* __restrict__ b21, const float* __restrict__ w22,
    const float* __restrict__ b22, float* __restrict__ out, int n) {
    __shared__ float g[128], t1[128], t2[128], t3[128], red[128];
    const int tid = threadIdx.x;
    g[tid] = pooled[tid] * (1.0f / (float)n);
    __syncthreads();

    float s = b11[tid];
    for (int k = 0; k < 128; ++k) s += g[k] * w11[k * 128 + tid];
    t1[tid] = fmaxf(s, 0.f);
    __syncthreads();

    s = b12[tid];
    for (int k = 0; k < 128; ++k) s += t1[k] * w12[k * 128 + tid];
    t2[tid] = s;
    __syncthreads();

    s = b21[tid];
    for (int k = 0; k < 128; ++k) s += t2[k] * w21[k * 128 + tid];
    t3[tid] = fmaxf(s, 0.f);
    __syncthreads();

    red[tid] = t3[tid] * w22[tid];
    __syncthreads();
    if (tid == 0) {
        float z = b22[0];
        for (int k = 0; k < 128; ++k) z += red[k];
        out[0] = 1.0f / (1.0f + expf(-z));
    }
}

extern "C" void kernel_launch(void* const* d_in, const int* in_sizes, int n_in,
                              void* d_out, int out_size, void* d_ws,
                              size_t ws_size, hipStream_t stream) {
    const float* x = (const float*)d_in[0];
    const int* ei = (const int*)d_in[1];
    const float* c1w = (const float*)d_in[2];
    const float* c1b = (const float*)d_in[3];
    const float* c2w = (const float*)d_in[4];
    const float* c2b = (const float*)d_in[5];
    const float* f1w1 = (const float*)d_in[6];
    const float* f1b1 = (const float*)d_in[7];
    const float* f1w2 = (const float*)d_in[8];
    const float* f1b2 = (const float*)d_in[9];
    const float* f2w1 = (const float*)d_in[10];
    const float* f2b1 = (const float*)d_in[11];
    const float* f2w2 = (const float*)d_in[12];
    const float* f2b2 = (const float*)d_in[13];
    float* out = (float*)d_out;

    const int N = in_sizes[0] / 128;
    const int E = in_sizes[1] / 2;
    const int ntiles = (N + TILE - 1) / TILE;  // 391
    const int M = ntiles * 8;                  // (tile, xcd) streams

    char* ws = (char*)d_ws;
    size_t off = 0;
    auto alloc = [&](size_t b) {
        size_t o = off;
        off += (b + 255) & ~(size_t)255;
        return o;
    };
    int* cnt = (int*)(ws + alloc((size_t)M * 4));
    int* start = (int*)(ws + alloc((size_t)(M + 1) * 4));
    int* cursor = (int*)(ws + alloc((size_t)M * 4));
    unsigned* bin = (unsigned*)(ws + alloc((size_t)E * 4));
    float* dinv = (float*)(ws + alloc((size_t)N * 4));
    float* pooled = (float*)(ws + alloc(512));
    unsigned short* wf1 = (unsigned short*)(ws + alloc(16384 * 2));
    unsigned short* wf2 = (unsigned short*)(ws + alloc(16384 * 2));
    unsigned short* hbuf = (unsigned short*)(ws + alloc((size_t)N * 128 * 2));
    unsigned short* abuf = (unsigned short*)(ws + alloc((size_t)N * 128 * 2));

    const int nbE = (E + 255) / 256;  // 3125
    const int nbG = (N + 63) / 64;    // 782

    k_zero<<<(M + 255) / 256, 256, 0, stream>>>(cnt, pooled, M);
    k_binA<<<nbE, 256, 0, stream>>>(ei + E, cnt, E);
    k_scanM<<<1, 256, 0, stream>>>(cnt, start, cursor, M, E);
    k_binB<<<nbE, 256, 0, stream>>>(ei, cursor, bin, E);
    k_degdinv<<<ntiles, 256, 0, stream>>>(bin, start, dinv, N);
    k_prepw<<<128, 256, 0, stream>>>(c1w, c2w, wf1, wf2);

    k_gemm_mfma<true><<<nbG, 256, 0, stream>>>(x, wf1, dinv, hbuf, N);
    k_aggT<<<ntiles, 256, 0, stream>>>((const unsigned*)hbuf, dinv, bin, start,
                                       c1b, (unsigned*)abuf, N);
    k_gemm_mfma<false><<<nbG, 256, 0, stream>>>(abuf, wf2, dinv, hbuf, N);
    k_aggT<<<ntiles, 256, 0, stream>>>((const unsigned*)hbuf, dinv, bin, start,
                                       c2b, (unsigned*)abuf, N);

    k_pool_bf16<<<256, 256, 0, stream>>>(abuf, pooled, N * 64);
    k_mlp<<<1, 128, 0, stream>>>(pooled, f1w1, f1b1, f1w2, f1b2, f2w1, f2b1,
                                 f2w2, f2b2, out, N);
}

// Round 6
// 410.069 us; speedup vs baseline: 4.3224x; 4.3224x over previous
//
#include <hip/hip_runtime.h>
#include <hip/hip_bf16.h>

// ---------------------------------------------------------------------------
// GCN graph classifier: 2x GCNConv(relu) -> mean pool -> MLP -> sigmoid
// Round 6: out[d] = relu(dinv[d]*(sum_{s in N(d)} h'[s] + h'[d]) + b),
//          h' = dinv * (A@W)  (dinv folded into GEMM epilogue).
// Build: bin 4B edge records by 128-node dst tile into per-(tile,XCD) append
// streams (write-combining), then per-tile LDS counting-sort -> sorted CSR +
// rowptr + dinv (no 50k-stream scatter, no global histogram).
// Aggregate: wave-per-node gather (12500 blocks) — high parallelism.
// ---------------------------------------------------------------------------

#define TILE 128

using short8 = __attribute__((ext_vector_type(8))) short;   // 8 bf16 (4 VGPR)
using f32x4  = __attribute__((ext_vector_type(4))) float;   // MFMA accum

__device__ inline unsigned short f2bf(float f) {  // RNE fp32 -> bf16
    unsigned u = __float_as_uint(f);
    u = (u + 0x7fff + ((u >> 16) & 1)) >> 16;
    return (unsigned short)u;
}
__device__ inline float bf2f(unsigned short b) {
    return __uint_as_float((unsigned)b << 16);
}

// ---- zero: per-(tile,xcd) counters + pooled accumulator --------------------
__global__ __launch_bounds__(256) void k_zero(int* __restrict__ cnt,
                                              float* __restrict__ pooled,
                                              int m) {
    int i = blockIdx.x * 256 + threadIdx.x;
    if (i < m) cnt[i] = 0;
    if (blockIdx.x == 0 && threadIdx.x < 128) pooled[threadIdx.x] = 0.0f;
}

// ---- binA: count edges per (dst tile, xcd-proxy) ---------------------------
__global__ __launch_bounds__(256) void k_binA(const int* __restrict__ dst,
                                              int* __restrict__ cnt, int e) {
    int i = blockIdx.x * 256 + threadIdx.x;
    if (i < e) {
        int t = dst[i] >> 7;
        atomicAdd(&cnt[t * 8 + (blockIdx.x & 7)], 1);
    }
}

// ---- scan of M counters (single block, serial chunks with carry) -----------
__global__ __launch_bounds__(256) void k_scanM(const int* __restrict__ cnt,
                                               int* __restrict__ start,
                                               int* __restrict__ cursor, int m,
                                               int etot) {
    __shared__ int sh[256];
    __shared__ int carry;
    const int tid = threadIdx.x;
    if (tid == 0) carry = 0;
    __syncthreads();
    const int nchunk = (m + 255) / 256;
    for (int c = 0; c < nchunk; ++c) {
        int i = c * 256 + tid;
        int v = (i < m) ? cnt[i] : 0;
        sh[tid] = v;
        __syncthreads();
        for (int o = 1; o < 256; o <<= 1) {
            int t = (tid >= o) ? sh[tid - o] : 0;
            __syncthreads();
            sh[tid] += t;
            __syncthreads();
        }
        int excl = sh[tid] - v + carry;
        if (i < m) {
            start[i] = excl;
            cursor[i] = excl;
        }
        __syncthreads();
        if (tid == 255) carry += sh[255];
        __syncthreads();
    }
    if (tid == 0) start[m] = etot;
}

// ---- binB: append 4B record (src<<7 | dst&127) via per-(tile,xcd) cursor ---
__global__ __launch_bounds__(256) void k_binB(const int* __restrict__ ei,
                                              int* __restrict__ cursor,
                                              unsigned* __restrict__ bin,
                                              int e) {
    int i = blockIdx.x * 256 + threadIdx.x;
    if (i < e) {
        int s = ei[i];
        int d = ei[e + i];
        int t = d >> 7;
        int pos = atomicAdd(&cursor[t * 8 + (blockIdx.x & 7)], 1);
        bin[pos] = ((unsigned)s << 7) | (unsigned)(d & 127);
    }
}

// ---- per-tile LDS counting sort: bin segment -> sorted csr + rowptr + dinv -
__global__ __launch_bounds__(256) void k_sortT(const unsigned* __restrict__ bin,
                                               const int* __restrict__ start,
                                               unsigned* __restrict__ csr,
                                               int* __restrict__ rowptr,
                                               float* __restrict__ dinv,
                                               int n) {
    __shared__ int deg[TILE], lrow[TILE], cur[TILE];
    const int t = blockIdx.x, tid = threadIdx.x;
    if (tid < TILE) {
        deg[tid] = 0;
        cur[tid] = 0;
    }
    __syncthreads();
    const int b = start[t * 8], e = start[t * 8 + 8];
    for (int j = b + tid; j < e; j += 256) atomicAdd(&deg[bin[j] & 127], 1);
    __syncthreads();
    if (tid < TILE) lrow[tid] = deg[tid];
    __syncthreads();
    for (int o = 1; o < TILE; o <<= 1) {
        int v = (tid >= o && tid < TILE) ? lrow[tid - o] : 0;
        __syncthreads();
        if (tid < TILE) lrow[tid] += v;
        __syncthreads();
    }
    if (tid < TILE) {
        const int excl = lrow[tid] - deg[tid];
        rowptr[t * TILE + tid] = b + excl;
        const int node = t * TILE + tid;
        if (node < n) dinv[node] = rsqrtf((float)deg[tid] + 1.0f);
        lrow[tid] = excl;  // now exclusive
    }
    if (tid == 0) rowptr[t * TILE + TILE] = e;  // boundary (consistent overlap)
    __syncthreads();
    for (int j = b + tid; j < e; j += 256) {
        const unsigned r = bin[j];
        const int dl = r & 127;
        const int p = atomicAdd(&cur[dl], 1);
        csr[b + lrow[dl] + p] = r >> 7;
    }
}

// ---- prep: convert both 128x128 weights to pre-fragged bf16 MFMA layout ----
// wf[((ct*4+ks)*64+l)*8+j] = W[ks*32 + (l>>4)*8 + j][ct*16 + (l&15)]
__global__ __launch_bounds__(256) void k_prepw(const float* __restrict__ w1,
                                               const float* __restrict__ w2,
                                               unsigned short* __restrict__ wf1,
                                               unsigned short* __restrict__ wf2) {
    int t = blockIdx.x * 256 + threadIdx.x;  // 0..32767
    int i = t & 16383;
    int j = i & 7;
    int l = (i >> 3) & 63;
    int ks = (i >> 9) & 3;
    int ct = (i >> 11) & 7;
    int k = ks * 32 + (l >> 4) * 8 + j;
    int c = ct * 16 + (l & 15);
    if (t < 16384)
        wf1[i] = f2bf(w1[k * 128 + c]);
    else
        wf2[i] = f2bf(w2[k * 128 + c]);
}

// ---- MFMA bf16 GEMM + dinv-scale epilogue: C = dinv[r]*(A@W), bf16 out -----
// 4 waves/block, 16 rows/wave. 16x16x32 frags; D: col=lane&15, row=(lane>>4)*4+i
template <bool AFP32>
__global__ __launch_bounds__(256) void k_gemm_mfma(
    const void* __restrict__ Ain, const unsigned short* __restrict__ Wf,
    const float* __restrict__ dinv, unsigned short* __restrict__ Cout,
    int nrows) {
    const int tid = threadIdx.x;
    const int wave = tid >> 6, l = tid & 63;
    const int r0w = blockIdx.x * 64 + wave * 16;
    const int mrow = l & 15, koff = (l >> 4) * 8;
    int r = r0w + mrow;
    int rload = (r < nrows) ? r : 0;

    short8 afr[4];
    if (AFP32) {
        const float* A = (const float*)Ain;
#pragma unroll
        for (int ks = 0; ks < 4; ++ks) {
            const float4 lo = *(const float4*)&A[(size_t)rload * 128 + ks * 32 + koff];
            const float4 hi = *(const float4*)&A[(size_t)rload * 128 + ks * 32 + koff + 4];
            short8 t;
            t[0] = (short)f2bf(lo.x); t[1] = (short)f2bf(lo.y);
            t[2] = (short)f2bf(lo.z); t[3] = (short)f2bf(lo.w);
            t[4] = (short)f2bf(hi.x); t[5] = (short)f2bf(hi.y);
            t[6] = (short)f2bf(hi.z); t[7] = (short)f2bf(hi.w);
            afr[ks] = t;
        }
    } else {
        const unsigned short* A = (const unsigned short*)Ain;
#pragma unroll
        for (int ks = 0; ks < 4; ++ks)
            afr[ks] = *(const short8*)&A[(size_t)rload * 128 + ks * 32 + koff];
    }

    f32x4 acc[8];
#pragma unroll
    for (int ct = 0; ct < 8; ++ct) acc[ct] = (f32x4){0.f, 0.f, 0.f, 0.f};

#pragma unroll
    for (int ct = 0; ct < 8; ++ct) {
#pragma unroll
        for (int ks = 0; ks < 4; ++ks) {
            const short8 b = *(const short8*)&Wf[((ct * 4 + ks) * 64 + l) * 8];
            acc[ct] = __builtin_amdgcn_mfma_f32_16x16x32_bf16(afr[ks], b,
                                                              acc[ct], 0, 0, 0);
        }
    }

    const int rs0 = r0w + (l >> 4) * 4;
    const int cc = l & 15;
    float dv[4];
#pragma unroll
    for (int i = 0; i < 4; ++i)
        dv[i] = (rs0 + i < nrows) ? dinv[rs0 + i] : 0.f;
#pragma unroll
    for (int ct = 0; ct < 8; ++ct) {
#pragma unroll
        for (int i = 0; i < 4; ++i) {
            const int rr = rs0 + i;
            if (rr < nrows)
                Cout[(size_t)rr * 128 + ct * 16 + cc] = f2bf(acc[ct][i] * dv[i]);
        }
    }
}

// ---- aggregate: wave per node; out = relu(dinv*(sum h'[s] + h'[d]) + b) ----
__global__ __launch_bounds__(256) void k_agg(
    const unsigned* __restrict__ hp,  // h' as uint[n][64] (2 bf16/uint)
    const float* __restrict__ dinv, const int* __restrict__ rowptr,
    const unsigned* __restrict__ csr, const float* __restrict__ bias,
    unsigned* __restrict__ outp, int n) {
    const int node = blockIdx.x * 4 + (threadIdx.x >> 6);
    if (node >= n) return;
    const int lane = threadIdx.x & 63;

    const float2 bp = *(const float2*)&bias[lane * 2];
    const unsigned hv = hp[(size_t)node * 64 + lane];
    float accx = bf2f((unsigned short)(hv & 0xffff));
    float accy = bf2f((unsigned short)(hv >> 16));

    int j = rowptr[node];
    const int end = rowptr[node + 1];
    for (; j + 3 < end; j += 4) {
        const unsigned s0 = csr[j], s1 = csr[j + 1], s2 = csr[j + 2],
                       s3 = csr[j + 3];
        const unsigned a0 = hp[(size_t)s0 * 64 + lane];
        const unsigned a1 = hp[(size_t)s1 * 64 + lane];
        const unsigned a2 = hp[(size_t)s2 * 64 + lane];
        const unsigned a3 = hp[(size_t)s3 * 64 + lane];
        accx += bf2f((unsigned short)(a0 & 0xffff)) +
                bf2f((unsigned short)(a1 & 0xffff)) +
                bf2f((unsigned short)(a2 & 0xffff)) +
                bf2f((unsigned short)(a3 & 0xffff));
        accy += bf2f((unsigned short)(a0 >> 16)) +
                bf2f((unsigned short)(a1 >> 16)) +
                bf2f((unsigned short)(a2 >> 16)) +
                bf2f((unsigned short)(a3 >> 16));
    }
    for (; j < end; ++j) {
        const unsigned a0 = hp[(size_t)csr[j] * 64 + lane];
        accx += bf2f((unsigned short)(a0 & 0xffff));
        accy += bf2f((unsigned short)(a0 >> 16));
    }
    const float dv = dinv[node];
    const unsigned short rx = f2bf(fmaxf(accx * dv + bp.x, 0.f));
    const unsigned short ry = f2bf(fmaxf(accy * dv + bp.y, 0.f));
    outp[(size_t)node * 64 + lane] = ((unsigned)ry << 16) | rx;
}

// ---- mean pool over bf16 [n,128]: block partials + atomic combine ----------
__global__ __launch_bounds__(256) void k_pool_bf16(
    const unsigned short* __restrict__ a, float* __restrict__ pooled,
    int npairs) {  // npairs = n*64 (uint = 2 cols)
    __shared__ float px[256], py[256];
    const int tid = threadIdx.x;
    float sx = 0.f, sy = 0.f;
    for (size_t idx = (size_t)blockIdx.x * 256 + tid; idx < (size_t)npairs;
         idx += (size_t)gridDim.x * 256) {
        const unsigned v = *(const unsigned*)&a[idx * 2];
        sx += bf2f((unsigned short)(v & 0xffff));
        sy += bf2f((unsigned short)(v >> 16));
    }
    px[tid] = sx;
    py[tid] = sy;
    __syncthreads();
    if (tid < 64) {
        const int c = tid;
        float ax = px[c] + px[c + 64] + px[c + 128] + px[c + 192];
        float ay = py[c] + py[c + 64] + py[c + 128] + py[c + 192];
        atomicAdd(&pooled[2 * c], ax);
        atomicAdd(&pooled[2 * c + 1], ay);
    }
}

// ---- MLP head: single block, 128 threads -----------------------------------
__global__ __launch_bounds__(128) void k_mlp(
    const float* __restrict__ pooled, const float* __restrict__ w11,
    const float* __restrict__ b11, const float* __restrict__ w12,
    const float* __restrict__ b12, const float* __restrict__ w21,
    const float* __restrict__ b21, const float* __restrict__ w22,
    const float* __restrict__ b22, float* __restrict__ out, int n) {
    __shared__ float g[128], t1[128], t2[128], t3[128], red[128];
    const int tid = threadIdx.x;
    g[tid] = pooled[tid] * (1.0f / (float)n);
    __syncthreads();

    float s = b11[tid];
    for (int k = 0; k < 128; ++k) s += g[k] * w11[k * 128 + tid];
    t1[tid] = fmaxf(s, 0.f);
    __syncthreads();

    s = b12[tid];
    for (int k = 0; k < 128; ++k) s += t1[k] * w12[k * 128 + tid];
    t2[tid] = s;
    __syncthreads();

    s = b21[tid];
    for (int k = 0; k < 128; ++k) s += t2[k] * w21[k * 128 + tid];
    t3[tid] = fmaxf(s, 0.f);
    __syncthreads();

    red[tid] = t3[tid] * w22[tid];
    __syncthreads();
    if (tid == 0) {
        float z = b22[0];
        for (int k = 0; k < 128; ++k) z += red[k];
        out[0] = 1.0f / (1.0f + expf(-z));
    }
}

extern "C" void kernel_launch(void* const* d_in, const int* in_sizes, int n_in,
                              void* d_out, int out_size, void* d_ws,
                              size_t ws_size, hipStream_t stream) {
    const float* x = (const float*)d_in[0];
    const int* ei = (const int*)d_in[1];
    const float* c1w = (const float*)d_in[2];
    const float* c1b = (const float*)d_in[3];
    const float* c2w = (const float*)d_in[4];
    const float* c2b = (const float*)d_in[5];
    const float* f1w1 = (const float*)d_in[6];
    const float* f1b1 = (const float*)d_in[7];
    const float* f1w2 = (const float*)d_in[8];
    const float* f1b2 = (const float*)d_in[9];
    const float* f2w1 = (const float*)d_in[10];
    const float* f2b1 = (const float*)d_in[11];
    const float* f2w2 = (const float*)d_in[12];
    const float* f2b2 = (const float*)d_in[13];
    float* out = (float*)d_out;

    const int N = in_sizes[0] / 128;
    const int E = in_sizes[1] / 2;
    const int ntiles = (N + TILE - 1) / TILE;  // 391
    const int M = ntiles * 8;                  // (tile, xcd) streams

    char* ws = (char*)d_ws;
    size_t off = 0;
    auto alloc = [&](size_t b) {
        size_t o = off;
        off += (b + 255) & ~(size_t)255;
        return o;
    };
    int* cnt = (int*)(ws + alloc((size_t)M * 4));
    int* start = (int*)(ws + alloc((size_t)(M + 1) * 4));
    int* cursor = (int*)(ws + alloc((size_t)M * 4));
    unsigned* bin = (unsigned*)(ws + alloc((size_t)E * 4));
    unsigned* csr = (unsigned*)(ws + alloc((size_t)E * 4));
    int* rowptr = (int*)(ws + alloc((size_t)(ntiles * TILE + 1) * 4));
    float* dinv = (float*)(ws + alloc((size_t)N * 4));
    float* pooled = (float*)(ws + alloc(512));
    unsigned short* wf1 = (unsigned short*)(ws + alloc(16384 * 2));
    unsigned short* wf2 = (unsigned short*)(ws + alloc(16384 * 2));
    unsigned short* hbuf = (unsigned short*)(ws + alloc((size_t)N * 128 * 2));
    unsigned short* abuf = (unsigned short*)(ws + alloc((size_t)N * 128 * 2));

    const int nbE = (E + 255) / 256;  // 3125
    const int nbG = (N + 63) / 64;    // 782

    k_zero<<<(M + 255) / 256, 256, 0, stream>>>(cnt, pooled, M);
    k_binA<<<nbE, 256, 0, stream>>>(ei + E, cnt, E);
    k_scanM<<<1, 256, 0, stream>>>(cnt, start, cursor, M, E);
    k_binB<<<nbE, 256, 0, stream>>>(ei, cursor, bin, E);
    k_sortT<<<ntiles, 256, 0, stream>>>(bin, start, csr, rowptr, dinv, N);
    k_prepw<<<128, 256, 0, stream>>>(c1w, c2w, wf1, wf2);

    k_gemm_mfma<true><<<nbG, 256, 0, stream>>>(x, wf1, dinv, hbuf, N);
    k_agg<<<(N + 3) / 4, 256, 0, stream>>>((const unsigned*)hbuf, dinv, rowptr,
                                           csr, c1b, (unsigned*)abuf, N);
    k_gemm_mfma<false><<<nbG, 256, 0, stream>>>(abuf, wf2, dinv, hbuf, N);
    k_agg<<<(N + 3) / 4, 256, 0, stream>>>((const unsigned*)hbuf, dinv, rowptr,
                                           csr, c2b, (unsigned*)abuf, N);

    k_pool_bf16<<<256, 256, 0, stream>>>(abuf, pooled, N * 64);
    k_mlp<<<1, 128, 0, stream>>>(pooled, f1w1, f1b1, f1w2, f1b2, f2w1, f2b1,
                                 f2w2, f2b2, out, N);
}

// Round 7
// 266.272 us; speedup vs baseline: 6.6566x; 1.5400x over previous
//
#include <hip/hip_runtime.h>
#include <hip/hip_bf16.h>

// ---------------------------------------------------------------------------
// GCN graph classifier: 2x GCNConv(relu) -> mean pool -> MLP -> sigmoid
// Round 7: out[d] = relu(dinv[d]*(sum_{s in N(d)} h'[s] + h'[d]) + b),
//          h' = dinv * (A@W)  (dinv folded into GEMM epilogue).
// Build = deterministic stable multisplit (NO global atomics):
//   histA: per-block LDS histogram over 391 dst-tiles -> hist[t][b]
//   scan1/scanB/scanAdd: exclusive scan of 76.6k counts
//   passB: re-read edges, LDS rank, write 4B records to exact contiguous
//          (tile,block) chunks  -> write-combining friendly
//   sortT: per-tile LDS counting sort -> sorted CSR + rowptr + dinv
// Aggregate: wave-per-node gather (12500 blocks). bf16 h', fp32 accum.
// ---------------------------------------------------------------------------

#define TILE 128
#define EPB 4096  // edges per multisplit block

using short8 = __attribute__((ext_vector_type(8))) short;   // 8 bf16 (4 VGPR)
using f32x4  = __attribute__((ext_vector_type(4))) float;   // MFMA accum

__device__ inline unsigned short f2bf(float f) {  // RNE fp32 -> bf16
    unsigned u = __float_as_uint(f);
    u = (u + 0x7fff + ((u >> 16) & 1)) >> 16;
    return (unsigned short)u;
}
__device__ inline float bf2f(unsigned short b) {
    return __uint_as_float((unsigned)b << 16);
}

// ---- histA: per-block LDS histogram of dst tiles; also zero pooled ---------
__global__ __launch_bounds__(256) void k_histA(const int* __restrict__ dst,
                                               int* __restrict__ hist,
                                               float* __restrict__ pooled,
                                               int e, int nt, int nb) {
    __shared__ int h[512];
    const int tid = threadIdx.x, b = blockIdx.x;
    for (int i = tid; i < 512; i += 256) h[i] = 0;
    if (b == 0 && tid < 128) pooled[tid] = 0.0f;
    __syncthreads();
    const int base = b * EPB;
#pragma unroll
    for (int k = 0; k < EPB / 256; ++k) {
        const int i = base + k * 256 + tid;
        if (i < e) atomicAdd(&h[dst[i] >> 7], 1);
    }
    __syncthreads();
    for (int t = tid; t < nt; t += 256) hist[t * nb + b] = h[t];
}

// ---- scan1: per-block exclusive scan + block sums --------------------------
__global__ __launch_bounds__(256) void k_scan1(const int* __restrict__ in,
                                               int* __restrict__ outp,
                                               int* __restrict__ bsum, int n) {
    __shared__ int sh[256];
    const int tid = threadIdx.x;
    const int i = blockIdx.x * 256 + tid;
    int v = (i < n) ? in[i] : 0;
    sh[tid] = v;
    __syncthreads();
    for (int o = 1; o < 256; o <<= 1) {
        int t = (tid >= o) ? sh[tid - o] : 0;
        __syncthreads();
        sh[tid] += t;
        __syncthreads();
    }
    if (i < n) outp[i] = sh[tid] - v;
    if (tid == 255) bsum[blockIdx.x] = sh[tid];
}

// ---- scanB: single-block scan of up to 1024 block sums (chunked+carry) -----
__global__ __launch_bounds__(256) void k_scanB(const int* __restrict__ bsum,
                                               int* __restrict__ bofs, int nb) {
    __shared__ int sh[256];
    __shared__ int carry;
    const int tid = threadIdx.x;
    if (tid == 0) carry = 0;
    __syncthreads();
    const int nchunk = (nb + 255) / 256;
    for (int c = 0; c < nchunk; ++c) {
        const int i = c * 256 + tid;
        int v = (i < nb) ? bsum[i] : 0;
        sh[tid] = v;
        __syncthreads();
        for (int o = 1; o < 256; o <<= 1) {
            int t = (tid >= o) ? sh[tid - o] : 0;
            __syncthreads();
            sh[tid] += t;
            __syncthreads();
        }
        if (i < nb) bofs[i] = sh[tid] - v + carry;
        __syncthreads();
        if (tid == 255) carry += sh[255];
        __syncthreads();
    }
}

// ---- scanAdd: add block offsets --------------------------------------------
__global__ __launch_bounds__(256) void k_scanAdd(int* __restrict__ data,
                                                 const int* __restrict__ bofs,
                                                 int n) {
    const int i = blockIdx.x * 256 + threadIdx.x;
    if (i < n) data[i] += bofs[blockIdx.x];
}

// ---- passB: stable multisplit scatter into exact (tile,block) chunks -------
__global__ __launch_bounds__(256) void k_passB(const int* __restrict__ ei,
                                               const int* __restrict__ histS,
                                               unsigned* __restrict__ bin,
                                               int e, int nt, int nb) {
    __shared__ int cnt[512], basei[512];
    const int tid = threadIdx.x, b = blockIdx.x;
    for (int i = tid; i < 512; i += 256) cnt[i] = 0;
    for (int t = tid; t < nt; t += 256) basei[t] = histS[t * nb + b];
    __syncthreads();
    const int base = b * EPB;
#pragma unroll
    for (int k = 0; k < EPB / 256; ++k) {
        const int i = base + k * 256 + tid;
        if (i < e) {
            const int s = ei[i];
            const int d = ei[e + i];
            const int t = d >> 7;
            const int r = atomicAdd(&cnt[t], 1);
            bin[basei[t] + r] = ((unsigned)s << 7) | (unsigned)(d & 127);
        }
    }
}

// ---- per-tile LDS counting sort: bin segment -> sorted csr + rowptr + dinv -
__global__ __launch_bounds__(256) void k_sortT(const unsigned* __restrict__ bin,
                                               const int* __restrict__ histS,
                                               unsigned* __restrict__ csr,
                                               int* __restrict__ rowptr,
                                               float* __restrict__ dinv,
                                               int n, int nt, int nb, int etot) {
    __shared__ int deg[TILE], lrow[TILE], cur[TILE];
    const int t = blockIdx.x, tid = threadIdx.x;
    if (tid < TILE) {
        deg[tid] = 0;
        cur[tid] = 0;
    }
    __syncthreads();
    const int b = histS[t * nb];
    const int e = (t + 1 < nt) ? histS[(t + 1) * nb] : etot;
    for (int j = b + tid; j < e; j += 256) atomicAdd(&deg[bin[j] & 127], 1);
    __syncthreads();
    if (tid < TILE) lrow[tid] = deg[tid];
    __syncthreads();
    for (int o = 1; o < TILE; o <<= 1) {
        int v = (tid >= o && tid < TILE) ? lrow[tid - o] : 0;
        __syncthreads();
        if (tid < TILE) lrow[tid] += v;
        __syncthreads();
    }
    if (tid < TILE) {
        const int excl = lrow[tid] - deg[tid];
        rowptr[t * TILE + tid] = b + excl;
        const int node = t * TILE + tid;
        if (node < n) dinv[node] = rsqrtf((float)deg[tid] + 1.0f);
        lrow[tid] = excl;
    }
    if (tid == 0) rowptr[t * TILE + TILE] = e;
    __syncthreads();
    for (int j = b + tid; j < e; j += 256) {
        const unsigned r = bin[j];
        const int dl = r & 127;
        const int p = atomicAdd(&cur[dl], 1);
        csr[b + lrow[dl] + p] = r >> 7;
    }
}

// ---- prep: convert both 128x128 weights to pre-fragged bf16 MFMA layout ----
// wf[((ct*4+ks)*64+l)*8+j] = W[ks*32 + (l>>4)*8 + j][ct*16 + (l&15)]
__global__ __launch_bounds__(256) void k_prepw(const float* __restrict__ w1,
                                               const float* __restrict__ w2,
                                               unsigned short* __restrict__ wf1,
                                               unsigned short* __restrict__ wf2) {
    int t = blockIdx.x * 256 + threadIdx.x;  // 0..32767
    int i = t & 16383;
    int j = i & 7;
    int l = (i >> 3) & 63;
    int ks = (i >> 9) & 3;
    int ct = (i >> 11) & 7;
    int k = ks * 32 + (l >> 4) * 8 + j;
    int c = ct * 16 + (l & 15);
    if (t < 16384)
        wf1[i] = f2bf(w1[k * 128 + c]);
    else
        wf2[i] = f2bf(w2[k * 128 + c]);
}

// ---- MFMA bf16 GEMM + dinv-scale epilogue: C = dinv[r]*(A@W), bf16 out -----
// 4 waves/block, 16 rows/wave. 16x16x32 frags; D: col=lane&15, row=(lane>>4)*4+i
template <bool AFP32>
__global__ __launch_bounds__(256) void k_gemm_mfma(
    const void* __restrict__ Ain, const unsigned short* __restrict__ Wf,
    const float* __restrict__ dinv, unsigned short* __restrict__ Cout,
    int nrows) {
    const int tid = threadIdx.x;
    const int wave = tid >> 6, l = tid & 63;
    const int r0w = blockIdx.x * 64 + wave * 16;
    const int mrow = l & 15, koff = (l >> 4) * 8;
    int r = r0w + mrow;
    int rload = (r < nrows) ? r : 0;

    short8 afr[4];
    if (AFP32) {
        const float* A = (const float*)Ain;
#pragma unroll
        for (int ks = 0; ks < 4; ++ks) {
            const float4 lo = *(const float4*)&A[(size_t)rload * 128 + ks * 32 + koff];
            const float4 hi = *(const float4*)&A[(size_t)rload * 128 + ks * 32 + koff + 4];
            short8 t;
            t[0] = (short)f2bf(lo.x); t[1] = (short)f2bf(lo.y);
            t[2] = (short)f2bf(lo.z); t[3] = (short)f2bf(lo.w);
            t[4] = (short)f2bf(hi.x); t[5] = (short)f2bf(hi.y);
            t[6] = (short)f2bf(hi.z); t[7] = (short)f2bf(hi.w);
            afr[ks] = t;
        }
    } else {
        const unsigned short* A = (const unsigned short*)Ain;
#pragma unroll
        for (int ks = 0; ks < 4; ++ks)
            afr[ks] = *(const short8*)&A[(size_t)rload * 128 + ks * 32 + koff];
    }

    f32x4 acc[8];
#pragma unroll
    for (int ct = 0; ct < 8; ++ct) acc[ct] = (f32x4){0.f, 0.f, 0.f, 0.f};

#pragma unroll
    for (int ct = 0; ct < 8; ++ct) {
#pragma unroll
        for (int ks = 0; ks < 4; ++ks) {
            const short8 b = *(const short8*)&Wf[((ct * 4 + ks) * 64 + l) * 8];
            acc[ct] = __builtin_amdgcn_mfma_f32_16x16x32_bf16(afr[ks], b,
                                                              acc[ct], 0, 0, 0);
        }
    }

    const int rs0 = r0w + (l >> 4) * 4;
    const int cc = l & 15;
    float dv[4];
#pragma unroll
    for (int i = 0; i < 4; ++i)
        dv[i] = (rs0 + i < nrows) ? dinv[rs0 + i] : 0.f;
#pragma unroll
    for (int ct = 0; ct < 8; ++ct) {
#pragma unroll
        for (int i = 0; i < 4; ++i) {
            const int rr = rs0 + i;
            if (rr < nrows)
                Cout[(size_t)rr * 128 + ct * 16 + cc] = f2bf(acc[ct][i] * dv[i]);
        }
    }
}

// ---- aggregate: wave per node; out = relu(dinv*(sum h'[s] + h'[d]) + b) ----
__global__ __launch_bounds__(256) void k_agg(
    const unsigned* __restrict__ hp,  // h' as uint[n][64] (2 bf16/uint)
    const float* __restrict__ dinv, const int* __restrict__ rowptr,
    const unsigned* __restrict__ csr, const float* __restrict__ bias,
    unsigned* __restrict__ outp, int n) {
    const int node = blockIdx.x * 4 + (threadIdx.x >> 6);
    if (node >= n) return;
    const int lane = threadIdx.x & 63;

    const float2 bp = *(const float2*)&bias[lane * 2];
    const unsigned hv = hp[(size_t)node * 64 + lane];
    float accx = bf2f((unsigned short)(hv & 0xffff));
    float accy = bf2f((unsigned short)(hv >> 16));

    int j = rowptr[node];
    const int end = rowptr[node + 1];
    for (; j + 3 < end; j += 4) {
        const unsigned s0 = csr[j], s1 = csr[j + 1], s2 = csr[j + 2],
                       s3 = csr[j + 3];
        const unsigned a0 = hp[(size_t)s0 * 64 + lane];
        const unsigned a1 = hp[(size_t)s1 * 64 + lane];
        const unsigned a2 = hp[(size_t)s2 * 64 + lane];
        const unsigned a3 = hp[(size_t)s3 * 64 + lane];
        accx += bf2f((unsigned short)(a0 & 0xffff)) +
                bf2f((unsigned short)(a1 & 0xffff)) +
                bf2f((unsigned short)(a2 & 0xffff)) +
                bf2f((unsigned short)(a3 & 0xffff));
        accy += bf2f((unsigned short)(a0 >> 16)) +
                bf2f((unsigned short)(a1 >> 16)) +
                bf2f((unsigned short)(a2 >> 16)) +
                bf2f((unsigned short)(a3 >> 16));
    }
    for (; j < end; ++j) {
        const unsigned a0 = hp[(size_t)csr[j] * 64 + lane];
        accx += bf2f((unsigned short)(a0 & 0xffff));
        accy += bf2f((unsigned short)(a0 >> 16));
    }
    const float dv = dinv[node];
    const unsigned short rx = f2bf(fmaxf(accx * dv + bp.x, 0.f));
    const unsigned short ry = f2bf(fmaxf(accy * dv + bp.y, 0.f));
    outp[(size_t)node * 64 + lane] = ((unsigned)ry << 16) | rx;
}

// ---- mean pool over bf16 [n,128]: block partials + atomic combine ----------
__global__ __launch_bounds__(256) void k_pool_bf16(
    const unsigned short* __restrict__ a, float* __restrict__ pooled,
    int npairs) {  // npairs = n*64 (uint = 2 cols)
    __shared__ float px[256], py[256];
    const int tid = threadIdx.x;
    float sx = 0.f, sy = 0.f;
    for (size_t idx = (size_t)blockIdx.x * 256 + tid; idx < (size_t)npairs;
         idx += (size_t)gridDim.x * 256) {
        const unsigned v = *(const unsigned*)&a[idx * 2];
        sx += bf2f((unsigned short)(v & 0xffff));
        sy += bf2f((unsigned short)(v >> 16));
    }
    px[tid] = sx;
    py[tid] = sy;
    __syncthreads();
    if (tid < 64) {
        const int c = tid;
        float ax = px[c] + px[c + 64] + px[c + 128] + px[c + 192];
        float ay = py[c] + py[c + 64] + py[c + 128] + py[c + 192];
        atomicAdd(&pooled[2 * c], ax);
        atomicAdd(&pooled[2 * c + 1], ay);
    }
}

// ---- MLP head: single block, 128 threads -----------------------------------
__global__ __launch_bounds__(128) void k_mlp(
    const float* __restrict__ pooled, const float* __restrict__ w11,
    const float* __restrict__ b11, const float* __restrict__ w12,
    const float* __restrict__ b12, const float* __restrict__ w21,
    const float* __restrict__ b21, const float* __restrict__ w22,
    const float* __restrict__ b22, float* __restrict__ out, int n) {
    __shared__ float g[128], t1[128], t2[128], t3[128], red[128];
    const int tid = threadIdx.x;
    g[tid] = pooled[tid] * (1.0f / (float)n);
    __syncthreads();

    float s = b11[tid];
    for (int k = 0; k < 128; ++k) s += g[k] * w11[k * 128 + tid];
    t1[tid] = fmaxf(s, 0.f);
    __syncthreads();

    s = b12[tid];
    for (int k = 0; k < 128; ++k) s += t1[k] * w12[k * 128 + tid];
    t2[tid] = s;
    __syncthreads();

    s = b21[tid];
    for (int k = 0; k < 128; ++k) s += t2[k] * w21[k * 128 + tid];
    t3[tid] = fmaxf(s, 0.f);
    __syncthreads();

    red[tid] = t3[tid] * w22[tid];
    __syncthreads();
    if (tid == 0) {
        float z = b22[0];
        for (int k = 0; k < 128; ++k) z += red[k];
        out[0] = 1.0f / (1.0f + expf(-z));
    }
}

extern "C" void kernel_launch(void* const* d_in, const int* in_sizes, int n_in,
                              void* d_out, int out_size, void* d_ws,
                              size_t ws_size, hipStream_t stream) {
    const float* x = (const float*)d_in[0];
    const int* ei = (const int*)d_in[1];
    const float* c1w = (const float*)d_in[2];
    const float* c1b = (const float*)d_in[3];
    const float* c2w = (const float*)d_in[4];
    const float* c2b = (const float*)d_in[5];
    const float* f1w1 = (const float*)d_in[6];
    const float* f1b1 = (const float*)d_in[7];
    const float* f1w2 = (const float*)d_in[8];
    const float* f1b2 = (const float*)d_in[9];
    const float* f2w1 = (const float*)d_in[10];
    const float* f2b1 = (const float*)d_in[11];
    const float* f2w2 = (const float*)d_in[12];
    const float* f2b2 = (const float*)d_in[13];
    float* out = (float*)d_out;

    const int N = in_sizes[0] / 128;
    const int E = in_sizes[1] / 2;
    const int NT = (N + TILE - 1) / TILE;    // 391
    const int NB = (E + EPB - 1) / EPB;      // 196
    const int NTB = NT * NB;                 // 76,636
    const int nbScan = (NTB + 255) / 256;    // 300

    char* ws = (char*)d_ws;
    size_t off = 0;
    auto alloc = [&](size_t b) {
        size_t o = off;
        off += (b + 255) & ~(size_t)255;
        return o;
    };
    int* hist = (int*)(ws + alloc((size_t)NTB * 4));
    int* histS = (int*)(ws + alloc((size_t)NTB * 4));
    int* bsum = (int*)(ws + alloc(4096));
    int* bofs = (int*)(ws + alloc(4096));
    unsigned* bin = (unsigned*)(ws + alloc((size_t)E * 4));
    unsigned* csr = (unsigned*)(ws + alloc((size_t)E * 4));
    int* rowptr = (int*)(ws + alloc((size_t)(NT * TILE + 1) * 4));
    float* dinv = (float*)(ws + alloc((size_t)N * 4));
    float* pooled = (float*)(ws + alloc(512));
    unsigned short* wf1 = (unsigned short*)(ws + alloc(16384 * 2));
    unsigned short* wf2 = (unsigned short*)(ws + alloc(16384 * 2));
    unsigned short* hbuf = (unsigned short*)(ws + alloc((size_t)N * 128 * 2));
    unsigned short* abuf = (unsigned short*)(ws + alloc((size_t)N * 128 * 2));

    const int nbG = (N + 63) / 64;  // 782

    k_histA<<<NB, 256, 0, stream>>>(ei + E, hist, pooled, E, NT, NB);
    k_scan1<<<nbScan, 256, 0, stream>>>(hist, histS, bsum, NTB);
    k_scanB<<<1, 256, 0, stream>>>(bsum, bofs, nbScan);
    k_scanAdd<<<nbScan, 256, 0, stream>>>(histS, bofs, NTB);
    k_passB<<<NB, 256, 0, stream>>>(ei, histS, bin, E, NT, NB);
    k_sortT<<<NT, 256, 0, stream>>>(bin, histS, csr, rowptr, dinv, N, NT, NB, E);
    k_prepw<<<128, 256, 0, stream>>>(c1w, c2w, wf1, wf2);

    k_gemm_mfma<true><<<nbG, 256, 0, stream>>>(x, wf1, dinv, hbuf, N);
    k_agg<<<(N + 3) / 4, 256, 0, stream>>>((const unsigned*)hbuf, dinv, rowptr,
                                           csr, c1b, (unsigned*)abuf, N);
    k_gemm_mfma<false><<<nbG, 256, 0, stream>>>(abuf, wf2, dinv, hbuf, N);
    k_agg<<<(N + 3) / 4, 256, 0, stream>>>((const unsigned*)hbuf, dinv, rowptr,
                                           csr, c2b, (unsigned*)abuf, N);

    k_pool_bf16<<<256, 256, 0, stream>>>(abuf, pooled, N * 64);
    k_mlp<<<1, 128, 0, stream>>>(pooled, f1w1, f1b1, f1w2, f1b2, f2w1, f2b1,
                                 f2w2, f2b2, out, N);
}

// Round 9
// 257.159 us; speedup vs baseline: 6.8925x; 1.0354x over previous
//
#include <hip/hip_runtime.h>
#include <hip/hip_bf16.h>

// ---------------------------------------------------------------------------
// GCN graph classifier: 2x GCNConv(relu) -> mean pool -> MLP -> sigmoid
// Round 8: agg reads 4 src rows per load instruction (4 nodes/wave,
// 16 lanes x uint4 = 1KB/instr gathers); prepw fused into histA.
// Build = deterministic stable multisplit (no global atomics) -> sorted CSR.
// h' = dinv*(A@W) via MFMA; out = relu(dinv*(sum h'[nbr] + h'[self]) + b).
// ---------------------------------------------------------------------------

#define TILE 128
#define EPB 4096  // edges per multisplit block

using short8 = __attribute__((ext_vector_type(8))) short;   // 8 bf16 (4 VGPR)
using f32x4  = __attribute__((ext_vector_type(4))) float;   // MFMA accum

__device__ inline unsigned short f2bf(float f) {  // RNE fp32 -> bf16
    unsigned u = __float_as_uint(f);
    u = (u + 0x7fff + ((u >> 16) & 1)) >> 16;
    return (unsigned short)u;
}
__device__ inline float bf2f(unsigned short b) {
    return __uint_as_float((unsigned)b << 16);
}
__device__ inline void acc8(float* a, const uint4 v) {
    a[0] += bf2f((unsigned short)(v.x & 0xffff));
    a[1] += bf2f((unsigned short)(v.x >> 16));
    a[2] += bf2f((unsigned short)(v.y & 0xffff));
    a[3] += bf2f((unsigned short)(v.y >> 16));
    a[4] += bf2f((unsigned short)(v.z & 0xffff));
    a[5] += bf2f((unsigned short)(v.z >> 16));
    a[6] += bf2f((unsigned short)(v.w & 0xffff));
    a[7] += bf2f((unsigned short)(v.w >> 16));
}

// ---- histA: per-block LDS histogram of dst tiles; + prepw + zero pooled ----
// wf[((ct*4+ks)*64+l)*8+j] = W[ks*32 + (l>>4)*8 + j][ct*16 + (l&15)]
__global__ __launch_bounds__(256) void k_histA(
    const int* __restrict__ dst, int* __restrict__ hist,
    float* __restrict__ pooled, const float* __restrict__ w1,
    const float* __restrict__ w2, unsigned short* __restrict__ wf1,
    unsigned short* __restrict__ wf2, int e, int nt, int nb) {
    __shared__ int h[512];
    const int tid = threadIdx.x, b = blockIdx.x;
    for (int i = tid; i < 512; i += 256) h[i] = 0;
    if (b == 0 && tid < 128) pooled[tid] = 0.0f;
    // fused weight prep: blocks 0..127 each convert 256 elements
    if (b < 128) {
        const int t = b * 256 + tid;  // 0..32767
        const int i = t & 16383;
        const int j = i & 7;
        const int l = (i >> 3) & 63;
        const int ks = (i >> 9) & 3;
        const int ct = (i >> 11) & 7;
        const int k = ks * 32 + (l >> 4) * 8 + j;
        const int c = ct * 16 + (l & 15);
        if (t < 16384)
            wf1[i] = f2bf(w1[k * 128 + c]);
        else
            wf2[i] = f2bf(w2[k * 128 + c]);
    }
    __syncthreads();
    const int base = b * EPB;
#pragma unroll
    for (int k = 0; k < EPB / 256; ++k) {
        const int i = base + k * 256 + tid;
        if (i < e) atomicAdd(&h[dst[i] >> 7], 1);
    }
    __syncthreads();
    for (int t = tid; t < nt; t += 256) hist[t * nb + b] = h[t];
}

// ---- scan1: per-block exclusive scan + block sums --------------------------
__global__ __launch_bounds__(256) void k_scan1(const int* __restrict__ in,
                                               int* __restrict__ outp,
                                               int* __restrict__ bsum, int n) {
    __shared__ int sh[256];
    const int tid = threadIdx.x;
    const int i = blockIdx.x * 256 + tid;
    int v = (i < n) ? in[i] : 0;
    sh[tid] = v;
    __syncthreads();
    for (int o = 1; o < 256; o <<= 1) {
        int t = (tid >= o) ? sh[tid - o] : 0;
        __syncthreads();
        sh[tid] += t;
        __syncthreads();
    }
    if (i < n) outp[i] = sh[tid] - v;
    if (tid == 255) bsum[blockIdx.x] = sh[tid];
}

// ---- scanB: single-block scan of block sums (chunked+carry) ----------------
__global__ __launch_bounds__(256) void k_scanB(const int* __restrict__ bsum,
                                               int* __restrict__ bofs, int nb) {
    __shared__ int sh[256];
    __shared__ int carry;
    const int tid = threadIdx.x;
    if (tid == 0) carry = 0;
    __syncthreads();
    const int nchunk = (nb + 255) / 256;
    for (int c = 0; c < nchunk; ++c) {
        const int i = c * 256 + tid;
        int v = (i < nb) ? bsum[i] : 0;
        sh[tid] = v;
        __syncthreads();
        for (int o = 1; o < 256; o <<= 1) {
            int t = (tid >= o) ? sh[tid - o] : 0;
            __syncthreads();
            sh[tid] += t;
            __syncthreads();
        }
        if (i < nb) bofs[i] = sh[tid] - v + carry;
        __syncthreads();
        if (tid == 255) carry += sh[255];
        __syncthreads();
    }
}

// ---- scanAdd: add block offsets --------------------------------------------
__global__ __launch_bounds__(256) void k_scanAdd(int* __restrict__ data,
                                                 const int* __restrict__ bofs,
                                                 int n) {
    const int i = blockIdx.x * 256 + threadIdx.x;
    if (i < n) data[i] += bofs[blockIdx.x];
}

// ---- passB: stable multisplit scatter into exact (tile,block) chunks -------
__global__ __launch_bounds__(256) void k_passB(const int* __restrict__ ei,
                                               const int* __restrict__ histS,
                                               unsigned* __restrict__ bin,
                                               int e, int nt, int nb) {
    __shared__ int cnt[512], basei[512];
    const int tid = threadIdx.x, b = blockIdx.x;
    for (int i = tid; i < 512; i += 256) cnt[i] = 0;
    for (int t = tid; t < nt; t += 256) basei[t] = histS[t * nb + b];
    __syncthreads();
    const int base = b * EPB;
#pragma unroll
    for (int k = 0; k < EPB / 256; ++k) {
        const int i = base + k * 256 + tid;
        if (i < e) {
            const int s = ei[i];
            const int d = ei[e + i];
            const int t = d >> 7;
            const int r = atomicAdd(&cnt[t], 1);
            bin[basei[t] + r] = ((unsigned)s << 7) | (unsigned)(d & 127);
        }
    }
}

// ---- per-tile LDS counting sort: bin segment -> sorted csr + rowptr + dinv -
__global__ __launch_bounds__(256) void k_sortT(const unsigned* __restrict__ bin,
                                               const int* __restrict__ histS,
                                               unsigned* __restrict__ csr,
                                               int* __restrict__ rowptr,
                                               float* __restrict__ dinv,
                                               int n, int nt, int nb, int etot) {
    __shared__ int deg[TILE], lrow[TILE], cur[TILE];
    const int t = blockIdx.x, tid = threadIdx.x;
    if (tid < TILE) {
        deg[tid] = 0;
        cur[tid] = 0;
    }
    __syncthreads();
    const int b = histS[t * nb];
    const int e = (t + 1 < nt) ? histS[(t + 1) * nb] : etot;
    for (int j = b + tid; j < e; j += 256) atomicAdd(&deg[bin[j] & 127], 1);
    __syncthreads();
    if (tid < TILE) lrow[tid] = deg[tid];
    __syncthreads();
    for (int o = 1; o < TILE; o <<= 1) {
        int v = (tid >= o && tid < TILE) ? lrow[tid - o] : 0;
        __syncthreads();
        if (tid < TILE) lrow[tid] += v;
        __syncthreads();
    }
    if (tid < TILE) {
        const int excl = lrow[tid] - deg[tid];
        rowptr[t * TILE + tid] = b + excl;
        const int node = t * TILE + tid;
        if (node < n) dinv[node] = rsqrtf((float)deg[tid] + 1.0f);
        lrow[tid] = excl;
    }
    if (tid == 0) rowptr[t * TILE + TILE] = e;
    __syncthreads();
    for (int j = b + tid; j < e; j += 256) {
        const unsigned r = bin[j];
        const int dl = r & 127;
        const int p = atomicAdd(&cur[dl], 1);
        csr[b + lrow[dl] + p] = r >> 7;
    }
}

// ---- MFMA bf16 GEMM + dinv-scale epilogue: C = dinv[r]*(A@W), bf16 out -----
// 4 waves/block, 16 rows/wave. 16x16x32 frags; D: col=lane&15, row=(lane>>4)*4+i
template <bool AFP32>
__global__ __launch_bounds__(256) void k_gemm_mfma(
    const void* __restrict__ Ain, const unsigned short* __restrict__ Wf,
    const float* __restrict__ dinv, unsigned short* __restrict__ Cout,
    int nrows) {
    const int tid = threadIdx.x;
    const int wave = tid >> 6, l = tid & 63;
    const int r0w = blockIdx.x * 64 + wave * 16;
    const int mrow = l & 15, koff = (l >> 4) * 8;
    int r = r0w + mrow;
    int rload = (r < nrows) ? r : 0;

    short8 afr[4];
    if (AFP32) {
        const float* A = (const float*)Ain;
#pragma unroll
        for (int ks = 0; ks < 4; ++ks) {
            const float4 lo = *(const float4*)&A[(size_t)rload * 128 + ks * 32 + koff];
            const float4 hi = *(const float4*)&A[(size_t)rload * 128 + ks * 32 + koff + 4];
            short8 t;
            t[0] = (short)f2bf(lo.x); t[1] = (short)f2bf(lo.y);
            t[2] = (short)f2bf(lo.z); t[3] = (short)f2bf(lo.w);
            t[4] = (short)f2bf(hi.x); t[5] = (short)f2bf(hi.y);
            t[6] = (short)f2bf(hi.z); t[7] = (short)f2bf(hi.w);
            afr[ks] = t;
        }
    } else {
        const unsigned short* A = (const unsigned short*)Ain;
#pragma unroll
        for (int ks = 0; ks < 4; ++ks)
            afr[ks] = *(const short8*)&A[(size_t)rload * 128 + ks * 32 + koff];
    }

    f32x4 acc[8];
#pragma unroll
    for (int ct = 0; ct < 8; ++ct) acc[ct] = (f32x4){0.f, 0.f, 0.f, 0.f};

#pragma unroll
    for (int ct = 0; ct < 8; ++ct) {
#pragma unroll
        for (int ks = 0; ks < 4; ++ks) {
            const short8 b = *(const short8*)&Wf[((ct * 4 + ks) * 64 + l) * 8];
            acc[ct] = __builtin_amdgcn_mfma_f32_16x16x32_bf16(afr[ks], b,
                                                              acc[ct], 0, 0, 0);
        }
    }

    const int rs0 = r0w + (l >> 4) * 4;
    const int cc = l & 15;
    float dv[4];
#pragma unroll
    for (int i = 0; i < 4; ++i)
        dv[i] = (rs0 + i < nrows) ? dinv[rs0 + i] : 0.f;
#pragma unroll
    for (int ct = 0; ct < 8; ++ct) {
#pragma unroll
        for (int i = 0; i < 4; ++i) {
            const int rr = rs0 + i;
            if (rr < nrows)
                Cout[(size_t)rr * 128 + ct * 16 + cc] = f2bf(acc[ct][i] * dv[i]);
        }
    }
}

// ---- aggregate: 4 nodes/wave, 16 lanes x uint4 per row (1KB per gather) ----
// out[d] = relu(dinv[d]*(sum h'[s] + h'[d]) + b)
__global__ __launch_bounds__(256) void k_agg(
    const uint4* __restrict__ hp4,  // h' as uint4[n][16]
    const float* __restrict__ dinv, const int* __restrict__ rowptr,
    const unsigned* __restrict__ csr, const float* __restrict__ bias,
    uint4* __restrict__ outp4, int n) {
    const int wave = threadIdx.x >> 6, lane = threadIdx.x & 63;
    const int g = lane >> 4, sl = lane & 15;
    const int node = (blockIdx.x * 4 + wave) * 4 + g;
    const bool valid = node < n;
    const int nd = valid ? node : 0;

    const int rb = rowptr[nd];
    const int deg = valid ? (rowptr[nd + 1] - rb) : 0;
    // wave-uniform max degree over the 4 groups
    int maxd = deg;
    maxd = max(maxd, __shfl_xor(maxd, 16));
    maxd = max(maxd, __shfl_xor(maxd, 32));

    float acc[8];
    {
        const uint4 z = {0u, 0u, 0u, 0u};
        uint4 self = valid ? hp4[(size_t)nd * 16 + sl] : z;
#pragma unroll
        for (int k = 0; k < 8; ++k) acc[k] = 0.f;
        acc8(acc, self);
    }

    int j = 0;
    for (; j + 3 < maxd; j += 4) {
        const uint4 z = {0u, 0u, 0u, 0u};
        uint4 v0 = z, v1 = z, v2 = z, v3 = z;
        if (j + 0 < deg) v0 = hp4[(size_t)csr[rb + j + 0] * 16 + sl];
        if (j + 1 < deg) v1 = hp4[(size_t)csr[rb + j + 1] * 16 + sl];
        if (j + 2 < deg) v2 = hp4[(size_t)csr[rb + j + 2] * 16 + sl];
        if (j + 3 < deg) v3 = hp4[(size_t)csr[rb + j + 3] * 16 + sl];
        acc8(acc, v0);
        acc8(acc, v1);
        acc8(acc, v2);
        acc8(acc, v3);
    }
    for (; j < maxd; ++j) {
        const uint4 z = {0u, 0u, 0u, 0u};
        uint4 v0 = z;
        if (j < deg) v0 = hp4[(size_t)csr[rb + j] * 16 + sl];
        acc8(acc, v0);
    }

    if (valid) {
        const float dv = dinv[nd];
        const float4 b0 = ((const float4*)bias)[sl * 2];
        const float4 b1 = ((const float4*)bias)[sl * 2 + 1];
        uint4 o;
        o.x = ((unsigned)f2bf(fmaxf(acc[1] * dv + b0.y, 0.f)) << 16) |
              f2bf(fmaxf(acc[0] * dv + b0.x, 0.f));
        o.y = ((unsigned)f2bf(fmaxf(acc[3] * dv + b0.w, 0.f)) << 16) |
              f2bf(fmaxf(acc[2] * dv + b0.z, 0.f));
        o.z = ((unsigned)f2bf(fmaxf(acc[5] * dv + b1.y, 0.f)) << 16) |
              f2bf(fmaxf(acc[4] * dv + b1.x, 0.f));
        o.w = ((unsigned)f2bf(fmaxf(acc[7] * dv + b1.w, 0.f)) << 16) |
              f2bf(fmaxf(acc[6] * dv + b1.z, 0.f));
        outp4[(size_t)nd * 16 + sl] = o;
    }
}

// ---- mean pool over bf16 [n,128]: block partials + atomic combine ----------
__global__ __launch_bounds__(256) void k_pool_bf16(
    const unsigned short* __restrict__ a, float* __restrict__ pooled,
    int npairs) {  // npairs = n*64 (uint = 2 cols)
    __shared__ float px[256], py[256];
    const int tid = threadIdx.x;
    float sx = 0.f, sy = 0.f;
    for (size_t idx = (size_t)blockIdx.x * 256 + tid; idx < (size_t)npairs;
         idx += (size_t)gridDim.x * 256) {
        const unsigned v = *(const unsigned*)&a[idx * 2];
        sx += bf2f((unsigned short)(v & 0xffff));
        sy += bf2f((unsigned short)(v >> 16));
    }
    px[tid] = sx;
    py[tid] = sy;
    __syncthreads();
    if (tid < 64) {
        const int c = tid;
        float ax = px[c] + px[c + 64] + px[c + 128] + px[c + 192];
        float ay = py[c] + py[c + 64] + py[c + 128] + py[c + 192];
        atomicAdd(&pooled[2 * c], ax);
        atomicAdd(&pooled[2 * c + 1], ay);
    }
}

// ---- MLP head: single block, 128 threads -----------------------------------
__global__ __launch_bounds__(128) void k_mlp(
    const float* __restrict__ pooled, const float* __restrict__ w11,
    const float* __restrict__ b11, const float* __restrict__ w12,
    const float* __restrict__ b12, const float* __restrict__ w21,
    const float* __restrict__ b21, const float* __restrict__ w22,
    const float* __restrict__ b22, float* __restrict__ out, int n) {
    __shared__ float g[128], t1[128], t2[128], t3[128], red[128];
    const int tid = threadIdx.x;
    g[tid] = pooled[tid] * (1.0f / (float)n);
    __syncthreads();

    float s = b11[tid];
    for (int k = 0; k < 128; ++k) s += g[k] * w11[k * 128 + tid];
    t1[tid] = fmaxf(s, 0.f);
    __syncthreads();

    s = b12[tid];
    for (int k = 0; k < 128; ++k) s += t1[k] * w12[k * 128 + tid];
    t2[tid] = s;
    __syncthreads();

    s = b21[tid];
    for (int k = 0; k < 128; ++k) s += t2[k] * w21[k * 128 + tid];
    t3[tid] = fmaxf(s, 0.f);
    __syncthreads();

    red[tid] = t3[tid] * w22[tid];
    __syncthreads();
    if (tid == 0) {
        float z = b22[0];
        for (int k = 0; k < 128; ++k) z += red[k];
        out[0] = 1.0f / (1.0f + expf(-z));
    }
}

extern "C" void kernel_launch(void* const* d_in, const int* in_sizes, int n_in,
                              void* d_out, int out_size, void* d_ws,
                              size_t ws_size, hipStream_t stream) {
    const float* x = (const float*)d_in[0];
    const int* ei = (const int*)d_in[1];
    const float* c1w = (const float*)d_in[2];
    const float* c1b = (const float*)d_in[3];
    const float* c2w = (const float*)d_in[4];
    const float* c2b = (const float*)d_in[5];
    const float* f1w1 = (const float*)d_in[6];
    const float* f1b1 = (const float*)d_in[7];
    const float* f1w2 = (const float*)d_in[8];
    const float* f1b2 = (const float*)d_in[9];
    const float* f2w1 = (const float*)d_in[10];
    const float* f2b1 = (const float*)d_in[11];
    const float* f2w2 = (const float*)d_in[12];
    const float* f2b2 = (const float*)d_in[13];
    float* out = (float*)d_out;

    const int N = in_sizes[0] / 128;
    const int E = in_sizes[1] / 2;
    const int NT = (N + TILE - 1) / TILE;    // 391
    const int NB = (E + EPB - 1) / EPB;      // 196
    const int NTB = NT * NB;                 // 76,636
    const int nbScan = (NTB + 255) / 256;    // 300

    char* ws = (char*)d_ws;
    size_t off = 0;
    auto alloc = [&](size_t b) {
        size_t o = off;
        off += (b + 255) & ~(size_t)255;
        return o;
    };
    int* hist = (int*)(ws + alloc((size_t)NTB * 4));
    int* histS = (int*)(ws + alloc((size_t)NTB * 4));
    int* bsum = (int*)(ws + alloc(4096));
    int* bofs = (int*)(ws + alloc(4096));
    unsigned* bin = (unsigned*)(ws + alloc((size_t)E * 4));
    unsigned* csr = (unsigned*)(ws + alloc((size_t)E * 4));
    int* rowptr = (int*)(ws + alloc((size_t)(NT * TILE + 1) * 4));
    float* dinv = (float*)(ws + alloc((size_t)N * 4));
    float* pooled = (float*)(ws + alloc(512));
    unsigned short* wf1 = (unsigned short*)(ws + alloc(16384 * 2));
    unsigned short* wf2 = (unsigned short*)(ws + alloc(16384 * 2));
    unsigned short* hbuf = (unsigned short*)(ws + alloc((size_t)N * 128 * 2));
    unsigned short* abuf = (unsigned short*)(ws + alloc((size_t)N * 128 * 2));

    const int nbG = (N + 63) / 64;  // 782

    k_histA<<<NB, 256, 0, stream>>>(ei + E, hist, pooled, c1w, c2w, wf1, wf2,
                                    E, NT, NB);
    k_scan1<<<nbScan, 256, 0, stream>>>(hist, histS, bsum, NTB);
    k_scanB<<<1, 256, 0, stream>>>(bsum, bofs, nbScan);
    k_scanAdd<<<nbScan, 256, 0, stream>>>(histS, bofs, NTB);
    k_passB<<<NB, 256, 0, stream>>>(ei, histS, bin, E, NT, NB);
    k_sortT<<<NT, 256, 0, stream>>>(bin, histS, csr, rowptr, dinv, N, NT, NB, E);

    k_gemm_mfma<true><<<nbG, 256, 0, stream>>>(x, wf1, dinv, hbuf, N);
    k_agg<<<(N + 15) / 16, 256, 0, stream>>>((const uint4*)hbuf, dinv, rowptr,
                                             csr, c1b, (uint4*)abuf, N);
    k_gemm_mfma<false><<<nbG, 256, 0, stream>>>(abuf, wf2, dinv, hbuf, N);
    k_agg<<<(N + 15) / 16, 256, 0, stream>>>((const uint4*)hbuf, dinv, rowptr,
                                             csr, c2b, (uint4*)abuf, N);

    k_pool_bf16<<<256, 256, 0, stream>>>(abuf, pooled, N * 64);
    k_mlp<<<1, 128, 0, stream>>>(pooled, f1w1, f1b1, f1w2, f1b2, f2w1, f2b1,
                                 f2w2, f2b2, out, N);
}